// Round 3
// baseline (8895.886 us; speedup 1.0000x reference)
//
#include <hip/hip_runtime.h>
#include <cstdint>
#include <cstddef>

// Elman RNN forward, MI355X. B=64, T=512, I=512, H=1024.
// d_out layout: hidden [B][T][H] then last_h [B][H].

#define Bsz 64
#define Tsz 512
#define Isz 512
#define Hsz 1024

// ---------------------------------------------------------------------------
// Kernel 1: xp = emb @ Wx^T + bx -> written into d_out's hidden region.
// (unchanged; measured ~380 us in round 1)
// ---------------------------------------------------------------------------
__global__ __launch_bounds__(256) void xp_gemm_f32(
    const float* __restrict__ A,    // [32768][512] embeddings
    const float* __restrict__ Wx,   // [1024][512]
    const float* __restrict__ bx,   // [1024]
    float* __restrict__ out)        // [32768][1024]
{
    __shared__ float As[16][128];   // k-major
    __shared__ float Bs[16][128];

    const int bid = blockIdx.x;
    const int m0 = (bid >> 3) << 7;
    const int n0 = (bid & 7) << 7;
    const int tid = (int)threadIdx.x;
    const int tx = tid & 15;
    const int ty = tid >> 4;

    float acc[8][8];
#pragma unroll
    for (int i = 0; i < 8; ++i)
#pragma unroll
        for (int j = 0; j < 8; ++j) acc[i][j] = 0.f;

    for (int kk = 0; kk < Isz; kk += 16) {
#pragma unroll
        for (int s = 0; s < 2; ++s) {
            const int f4 = (s << 8) + tid;
            const int r  = f4 >> 2;
            const int kq = (f4 & 3) << 2;
            const float4 a = *(const float4*)(A  + (size_t)(m0 + r) * Isz + kk + kq);
            const float4 b = *(const float4*)(Wx + (size_t)(n0 + r) * Isz + kk + kq);
            As[kq + 0][r] = a.x; As[kq + 1][r] = a.y; As[kq + 2][r] = a.z; As[kq + 3][r] = a.w;
            Bs[kq + 0][r] = b.x; Bs[kq + 1][r] = b.y; Bs[kq + 2][r] = b.z; Bs[kq + 3][r] = b.w;
        }
        __syncthreads();
#pragma unroll
        for (int k = 0; k < 16; ++k) {
            const float4 a0 = *(const float4*)&As[k][ty * 8];
            const float4 a1 = *(const float4*)&As[k][ty * 8 + 4];
            const float4 b0 = *(const float4*)&Bs[k][tx * 8];
            const float4 b1 = *(const float4*)&Bs[k][tx * 8 + 4];
            const float ar[8] = {a0.x, a0.y, a0.z, a0.w, a1.x, a1.y, a1.z, a1.w};
            const float br[8] = {b0.x, b0.y, b0.z, b0.w, b1.x, b1.y, b1.z, b1.w};
#pragma unroll
            for (int i = 0; i < 8; ++i)
#pragma unroll
                for (int j = 0; j < 8; ++j)
                    acc[i][j] = fmaf(ar[i], br[j], acc[i][j]);
        }
        __syncthreads();
    }

    float bxr[8];
#pragma unroll
    for (int j = 0; j < 8; ++j) bxr[j] = bx[n0 + tx * 8 + j];

#pragma unroll
    for (int i = 0; i < 8; ++i) {
        const size_t row = (size_t)(m0 + ty * 8 + i) * Hsz + (size_t)(n0 + tx * 8);
        float4 o0, o1;
        o0.x = acc[i][0] + bxr[0]; o0.y = acc[i][1] + bxr[1];
        o0.z = acc[i][2] + bxr[2]; o0.w = acc[i][3] + bxr[3];
        o1.x = acc[i][4] + bxr[4]; o1.y = acc[i][5] + bxr[5];
        o1.z = acc[i][6] + bxr[6]; o1.w = acc[i][7] + bxr[7];
        *(float4*)(out + row)     = o0;
        *(float4*)(out + row + 4) = o1;
    }
}

// ---------------------------------------------------------------------------
// Async global->LDS 16B stage (wave-linear LDS dest: base + lane*16).
// ---------------------------------------------------------------------------
__device__ __forceinline__ void stage16(const float* gsrc, float* ldst) {
#if __has_builtin(__builtin_amdgcn_global_load_lds)
    __builtin_amdgcn_global_load_lds(
        (const __attribute__((address_space(1))) uint32_t*)gsrc,
        (__attribute__((address_space(3))) uint32_t*)ldst, 16, 0, 0);
#else
    *(float4*)ldst = *(const float4*)gsrc;
#endif
}

// ---------------------------------------------------------------------------
// Kernel 2: persistent scan. h_t = tanh(xp_t + h_{t-1} @ Wh^T + bh), in place
// over d_out's hidden region; writes last_h tail at t=T-1.
//
// Grid 256 wg x 256 thr (1 wg/CU, all co-resident).
// wg -> (bT = wg&7, jT = wg>>3). Sync group bT = 32 wgs covering batch rows
// bT*8..bT*8+7; wg owns 32 output channels jT*32..+31.
// Thread roles: ks = tid&31 (k lane, k = i*128 + ks*4 + q), jg = (tid>>5)&3
// (8-ch group), rw = tid>>7 (4-row half). Wh chunk whr[8][32] in registers
// for all 512 steps (256 VGPR; 1 wg/CU so 512 VGPR/wave available).
// Reduction over the 32 ks lanes via register butterfly (shfl_xor); after 5
// stages lane ks owns output (row rw*4+(ks>>3), ch jg*8+(ks&7)).
// Sync protocol: EXACTLY round 1's proven one (agent-scope relaxed atomic h
// stores -> vmcnt(0) -> barrier -> release flag; relaxed polls -> barrier ->
// agent acquire fence). Flags padded to 64 B; poison 0xAA < 0 => no init.
// ---------------------------------------------------------------------------
__global__ __launch_bounds__(256, 1) void rnn_scan_f32(
    const float* __restrict__ h0,    // [64][1024]
    const float* __restrict__ Wh,    // [1024][1024]
    const float* __restrict__ bh,    // [1024]
    float* __restrict__ out,         // hidden [64][512][1024] + last [64][1024]
    int* __restrict__ flags)         // d_ws: [256 slots][16 ints] (64 B stride)
{
    __shared__ float hs[8 * 1024];   // h tile: 8 rows x 1024 floats, 32 KB

    const int wg  = (int)blockIdx.x;
    const int bT  = wg & 7;
    const int jT  = wg >> 3;
    const int tid = (int)threadIdx.x;
    const int ks  = tid & 31;
    const int jg  = (tid >> 5) & 3;
    const int rw  = tid >> 7;

    // Wh chunk in registers: ch = jT*32 + jg*8 + jj ; k = i*128 + ks*4 + q
    float whr[8][32];
#pragma unroll
    for (int jj = 0; jj < 8; ++jj) {
        const float* wrow = Wh + (size_t)(jT * 32 + jg * 8 + jj) * Hsz;
#pragma unroll
        for (int i = 0; i < 8; ++i) {
            const float4 w = *(const float4*)(wrow + i * 128 + ks * 4);
            whr[jj][i * 4 + 0] = w.x; whr[jj][i * 4 + 1] = w.y;
            whr[jj][i * 4 + 2] = w.z; whr[jj][i * 4 + 3] = w.w;
        }
    }

    const int myrow = bT * 8 + rw * 4 + (ks >> 3);   // butterfly output owner
    const int mych  = jT * 32 + jg * 8 + (ks & 7);
    const float bias = bh[mych];
    const int myflag = (bT * 32 + jT) * 16;

    for (int t = 0; t < Tsz; ++t) {
        const size_t oidx = ((size_t)myrow * Tsz + t) * Hsz + mych;
        const float xpv = out[oidx];   // prefetch xp; overlaps the spin below

        if (t > 0) {
            if (tid < 32) {
                const int* fp = &flags[(bT * 32 + tid) * 16];
                while (__hip_atomic_load(fp, __ATOMIC_RELAXED,
                                         __HIP_MEMORY_SCOPE_AGENT) < t) {}
            }
            __syncthreads();
            __builtin_amdgcn_fence(__ATOMIC_ACQUIRE, "agent");
        }

        // Stage h_{t-1} tile [8][1024] into LDS via global_load_lds (16B/lane).
#pragma unroll
        for (int bb = 0; bb < 8; ++bb) {
            const float* src = (t == 0)
                ? (h0 + (size_t)(bT * 8 + bb) * Hsz + tid * 4)
                : (out + ((size_t)(bT * 8 + bb) * Tsz + (t - 1)) * Hsz + tid * 4);
            stage16(src, hs + bb * 1024 + tid * 4);
        }
        asm volatile("s_waitcnt vmcnt(0)" ::: "memory");
        __syncthreads();

        // Partial dots: 4 rows x 8 ch, k = i*128 + ks*4 + q (float4 LDS reads,
        // conflict-free: 32 lanes x 16B contiguous; lane pairs broadcast).
        float pacc[4][8];
#pragma unroll
        for (int bb = 0; bb < 4; ++bb)
#pragma unroll
            for (int jj = 0; jj < 8; ++jj) pacc[bb][jj] = 0.f;

#pragma unroll
        for (int bb = 0; bb < 4; ++bb) {
            const float* hrow = hs + (rw * 4 + bb) * 1024 + ks * 4;
#pragma unroll
            for (int i = 0; i < 8; ++i) {
                const float4 hv = *(const float4*)(hrow + i * 128);
#pragma unroll
                for (int jj = 0; jj < 8; ++jj) {
                    pacc[bb][jj] = fmaf(hv.x, whr[jj][i * 4 + 0], pacc[bb][jj]);
                    pacc[bb][jj] = fmaf(hv.y, whr[jj][i * 4 + 1], pacc[bb][jj]);
                    pacc[bb][jj] = fmaf(hv.z, whr[jj][i * 4 + 2], pacc[bb][jj]);
                    pacc[bb][jj] = fmaf(hv.w, whr[jj][i * 4 + 3], pacc[bb][jj]);
                }
            }
        }

        // Register butterfly over the 32 ks lanes; output p = bb*8 + jj.
        // Invariant before stage s (m=2^s): lane l pos i -> output i*m + (l&(m-1)).
        float v[32];
#pragma unroll
        for (int bb = 0; bb < 4; ++bb)
#pragma unroll
            for (int jj = 0; jj < 8; ++jj) v[bb * 8 + jj] = pacc[bb][jj];

#pragma unroll
        for (int s = 0; s < 5; ++s) {
            const int m = 1 << s;
            const int cnt = 32 >> (s + 1);
            const bool hi = (ks & m) != 0;
#pragma unroll
            for (int i = 0; i < cnt; ++i) {
                const float keep = hi ? v[2 * i + 1] : v[2 * i];
                const float send = hi ? v[2 * i]     : v[2 * i + 1];
                const float recv = __shfl_xor(send, m, 64);
                v[i] = keep + recv;
            }
        }
        const float ssum = v[0];

        const float z = xpv + ssum + bias;
        const float e = __expf(2.f * z);        // tanh(z) = 1 - 2/(e^{2z}+1)
        const float h = 1.f - 2.f / (e + 1.f);

        __hip_atomic_store(&out[oidx], h, __ATOMIC_RELAXED,
                           __HIP_MEMORY_SCOPE_AGENT);
        if (t == Tsz - 1)
            out[(size_t)Bsz * Tsz * Hsz + (size_t)myrow * Hsz + mych] = h;

        asm volatile("s_waitcnt vmcnt(0)" ::: "memory");  // own stores drained
        __syncthreads();                                   // whole wg drained
        if (tid == 0)
            __hip_atomic_store(&flags[myflag], t + 1, __ATOMIC_RELEASE,
                               __HIP_MEMORY_SCOPE_AGENT);
    }
}

// ---------------------------------------------------------------------------
extern "C" void kernel_launch(void* const* d_in, const int* in_sizes, int n_in,
                              void* d_out, int out_size, void* d_ws, size_t ws_size,
                              hipStream_t stream) {
    const float* emb = (const float*)d_in[0];
    const float* h0  = (const float*)d_in[1];
    const float* Wx  = (const float*)d_in[2];
    const float* bx  = (const float*)d_in[3];
    const float* Wh  = (const float*)d_in[4];
    const float* bh  = (const float*)d_in[5];
    float* out = (float*)d_out;
    int* flags = (int*)d_ws;   // 256*16 ints; 0xAA poison is negative => no init

    hipLaunchKernelGGL(xp_gemm_f32, dim3(2048), dim3(256), 0, stream,
                       emb, Wx, bx, out);
    hipLaunchKernelGGL(rnn_scan_f32, dim3(256), dim3(256), 0, stream,
                       h0, Wh, bh, out, flags);
}

// Round 4
// 3659.597 us; speedup vs baseline: 2.4308x; 2.4308x over previous
//
#include <hip/hip_runtime.h>
#include <cstdint>
#include <cstddef>

// Elman RNN forward, MI355X. B=64, T=512, I=512, H=1024.
// d_out layout: hidden [B][T][H] then last_h [B][H].

#define Bsz 64
#define Tsz 512
#define Isz 512
#define Hsz 1024

// ---------------------------------------------------------------------------
// Kernel 1: xp = emb @ Wx^T + bx -> written into d_out's hidden region.
// (unchanged; measured ~380 us in round 1)
// ---------------------------------------------------------------------------
__global__ __launch_bounds__(256) void xp_gemm_f32(
    const float* __restrict__ A,    // [32768][512] embeddings
    const float* __restrict__ Wx,   // [1024][512]
    const float* __restrict__ bx,   // [1024]
    float* __restrict__ out)        // [32768][1024]
{
    __shared__ float As[16][128];   // k-major
    __shared__ float Bs[16][128];

    const int bid = blockIdx.x;
    const int m0 = (bid >> 3) << 7;
    const int n0 = (bid & 7) << 7;
    const int tid = (int)threadIdx.x;
    const int tx = tid & 15;
    const int ty = tid >> 4;

    float acc[8][8];
#pragma unroll
    for (int i = 0; i < 8; ++i)
#pragma unroll
        for (int j = 0; j < 8; ++j) acc[i][j] = 0.f;

    for (int kk = 0; kk < Isz; kk += 16) {
#pragma unroll
        for (int s = 0; s < 2; ++s) {
            const int f4 = (s << 8) + tid;
            const int r  = f4 >> 2;
            const int kq = (f4 & 3) << 2;
            const float4 a = *(const float4*)(A  + (size_t)(m0 + r) * Isz + kk + kq);
            const float4 b = *(const float4*)(Wx + (size_t)(n0 + r) * Isz + kk + kq);
            As[kq + 0][r] = a.x; As[kq + 1][r] = a.y; As[kq + 2][r] = a.z; As[kq + 3][r] = a.w;
            Bs[kq + 0][r] = b.x; Bs[kq + 1][r] = b.y; Bs[kq + 2][r] = b.z; Bs[kq + 3][r] = b.w;
        }
        __syncthreads();
#pragma unroll
        for (int k = 0; k < 16; ++k) {
            const float4 a0 = *(const float4*)&As[k][ty * 8];
            const float4 a1 = *(const float4*)&As[k][ty * 8 + 4];
            const float4 b0 = *(const float4*)&Bs[k][tx * 8];
            const float4 b1 = *(const float4*)&Bs[k][tx * 8 + 4];
            const float ar[8] = {a0.x, a0.y, a0.z, a0.w, a1.x, a1.y, a1.z, a1.w};
            const float br[8] = {b0.x, b0.y, b0.z, b0.w, b1.x, b1.y, b1.z, b1.w};
#pragma unroll
            for (int i = 0; i < 8; ++i)
#pragma unroll
                for (int j = 0; j < 8; ++j)
                    acc[i][j] = fmaf(ar[i], br[j], acc[i][j]);
        }
        __syncthreads();
    }

    float bxr[8];
#pragma unroll
    for (int j = 0; j < 8; ++j) bxr[j] = bx[n0 + tx * 8 + j];

#pragma unroll
    for (int i = 0; i < 8; ++i) {
        const size_t row = (size_t)(m0 + ty * 8 + i) * Hsz + (size_t)(n0 + tx * 8);
        float4 o0, o1;
        o0.x = acc[i][0] + bxr[0]; o0.y = acc[i][1] + bxr[1];
        o0.z = acc[i][2] + bxr[2]; o0.w = acc[i][3] + bxr[3];
        o1.x = acc[i][4] + bxr[4]; o1.y = acc[i][5] + bxr[5];
        o1.z = acc[i][6] + bxr[6]; o1.w = acc[i][7] + bxr[7];
        *(float4*)(out + row)     = o0;
        *(float4*)(out + row + 4) = o1;
    }
}

// ---------------------------------------------------------------------------
// Async global->LDS 16B stage (wave-linear LDS dest: base + lane*16).
// ---------------------------------------------------------------------------
__device__ __forceinline__ void stage16(const float* gsrc, float* ldst) {
#if __has_builtin(__builtin_amdgcn_global_load_lds)
    __builtin_amdgcn_global_load_lds(
        (const __attribute__((address_space(1))) uint32_t*)gsrc,
        (__attribute__((address_space(3))) uint32_t*)ldst, 16, 0, 0);
#else
    *(float4*)ldst = *(const float4*)gsrc;
#endif
}

// ---------------------------------------------------------------------------
// Kernel 2: persistent scan. h_t = tanh(xp_t + h_{t-1} @ Wh^T + bh), in place
// over d_out's hidden region; writes last_h tail at t=T-1.
//
// FENCE-FREE coherence design (the round-3 fences were cache-wide ops:
// agent-acquire => buffer_inv sc0 sc1 (L1+L2 invalidate), agent-release
// store => buffer_wbl2 (full L2 writeback) -- per step per wg = disaster).
// Invariants replacing them:
//  * h stores + flag store + flag polls + xp reads: relaxed AGENT atomics
//    (coherent at the Infinity Cache, no fence, never cached in L1/L2).
//  * h staging loads are plain/cached BUT provably never stale: address
//    (row, t-1, :) is first touched at step t (unique per step), and no
//    cached load ever touches the hidden region (xp reads are coherent),
//    so no stale line can exist in any L1/L2.
//  * Ordering producer-side: h stores -> s_waitcnt vmcnt(0) (acked at
//    coherence point) -> barrier -> relaxed flag store.
// Grid 256 wg x 256 thr (1 wg/CU). wg -> (bT = wg&7, jT = wg>>3); group bT =
// 32 wgs sharing batch rows bT*8..+7; wg owns channels jT*32..+31.
// whr[8][32] weight chunk in registers all 512 steps; butterfly reduce.
// Flags padded to 64 B; poison 0xAA < 0 => no init needed.
// ---------------------------------------------------------------------------
__global__ __launch_bounds__(256, 1) void rnn_scan_f32(
    const float* __restrict__ h0,    // [64][1024]
    const float* __restrict__ Wh,    // [1024][1024]
    const float* __restrict__ bh,    // [1024]
    float* __restrict__ out,         // hidden [64][512][1024] + last [64][1024]
    int* __restrict__ flags)         // d_ws: [256 slots][16 ints] (64 B stride)
{
    __shared__ float hs[8 * 1024];   // h tile: 8 rows x 1024 floats, 32 KB

    const int wg  = (int)blockIdx.x;
    const int bT  = wg & 7;
    const int jT  = wg >> 3;
    const int tid = (int)threadIdx.x;
    const int ks  = tid & 31;
    const int jg  = (tid >> 5) & 3;
    const int rw  = tid >> 7;

    // Wh chunk in registers: ch = jT*32 + jg*8 + jj ; k = i*128 + ks*4 + q
    float whr[8][32];
#pragma unroll
    for (int jj = 0; jj < 8; ++jj) {
        const float* wrow = Wh + (size_t)(jT * 32 + jg * 8 + jj) * Hsz;
#pragma unroll
        for (int i = 0; i < 8; ++i) {
            const float4 w = *(const float4*)(wrow + i * 128 + ks * 4);
            whr[jj][i * 4 + 0] = w.x; whr[jj][i * 4 + 1] = w.y;
            whr[jj][i * 4 + 2] = w.z; whr[jj][i * 4 + 3] = w.w;
        }
    }

    const int myrow = bT * 8 + rw * 4 + (ks >> 3);   // butterfly output owner
    const int mych  = jT * 32 + jg * 8 + (ks & 7);
    const float bias = bh[mych];
    const int myflag = (bT * 32 + jT) * 16;

    for (int t = 0; t < Tsz; ++t) {
        const size_t oidx = ((size_t)myrow * Tsz + t) * Hsz + mych;
        // Coherent xp prefetch (never fills L1/L2; overlaps the spin below).
        const float xpv = __hip_atomic_load(&out[oidx], __ATOMIC_RELAXED,
                                            __HIP_MEMORY_SCOPE_AGENT);

        if (t > 0) {
            if (tid < 32) {
                const int* fp = &flags[(bT * 32 + tid) * 16];
                while (__hip_atomic_load(fp, __ATOMIC_RELAXED,
                                         __HIP_MEMORY_SCOPE_AGENT) < t)
                    __builtin_amdgcn_s_sleep(1);
            }
            __syncthreads();
            // NO acquire fence: staging addresses are first-touch (see header).
        }

        // Stage h_{t-1} tile [8][1024] into LDS via global_load_lds (16B/lane).
#pragma unroll
        for (int bb = 0; bb < 8; ++bb) {
            const float* src = (t == 0)
                ? (h0 + (size_t)(bT * 8 + bb) * Hsz + tid * 4)
                : (out + ((size_t)(bT * 8 + bb) * Tsz + (t - 1)) * Hsz + tid * 4);
            stage16(src, hs + bb * 1024 + tid * 4);
        }
        asm volatile("s_waitcnt vmcnt(0)" ::: "memory");
        __syncthreads();

        // Partial dots: 4 rows x 8 ch, k = i*128 + ks*4 + q (float4 LDS reads,
        // conflict-free: 32 lanes x 16B contiguous; lane pairs broadcast).
        float pacc[4][8];
#pragma unroll
        for (int bb = 0; bb < 4; ++bb)
#pragma unroll
            for (int jj = 0; jj < 8; ++jj) pacc[bb][jj] = 0.f;

#pragma unroll
        for (int bb = 0; bb < 4; ++bb) {
            const float* hrow = hs + (rw * 4 + bb) * 1024 + ks * 4;
#pragma unroll
            for (int i = 0; i < 8; ++i) {
                const float4 hv = *(const float4*)(hrow + i * 128);
#pragma unroll
                for (int jj = 0; jj < 8; ++jj) {
                    pacc[bb][jj] = fmaf(hv.x, whr[jj][i * 4 + 0], pacc[bb][jj]);
                    pacc[bb][jj] = fmaf(hv.y, whr[jj][i * 4 + 1], pacc[bb][jj]);
                    pacc[bb][jj] = fmaf(hv.z, whr[jj][i * 4 + 2], pacc[bb][jj]);
                    pacc[bb][jj] = fmaf(hv.w, whr[jj][i * 4 + 3], pacc[bb][jj]);
                }
            }
        }

        // Register butterfly over the 32 ks lanes; output p = bb*8 + jj.
        // Invariant before stage s (m=2^s): lane l pos i -> output i*m + (l&(m-1)).
        float v[32];
#pragma unroll
        for (int bb = 0; bb < 4; ++bb)
#pragma unroll
            for (int jj = 0; jj < 8; ++jj) v[bb * 8 + jj] = pacc[bb][jj];

#pragma unroll
        for (int s = 0; s < 5; ++s) {
            const int m = 1 << s;
            const int cnt = 32 >> (s + 1);
            const bool hi = (ks & m) != 0;
#pragma unroll
            for (int i = 0; i < cnt; ++i) {
                const float keep = hi ? v[2 * i + 1] : v[2 * i];
                const float send = hi ? v[2 * i]     : v[2 * i + 1];
                const float recv = __shfl_xor(send, m, 64);
                v[i] = keep + recv;
            }
        }
        const float ssum = v[0];

        const float z = xpv + ssum + bias;
        const float e = __expf(2.f * z);        // tanh(z) = 1 - 2/(e^{2z}+1)
        const float h = 1.f - 2.f / (e + 1.f);

        __hip_atomic_store(&out[oidx], h, __ATOMIC_RELAXED,
                           __HIP_MEMORY_SCOPE_AGENT);
        if (t == Tsz - 1)
            out[(size_t)Bsz * Tsz * Hsz + (size_t)myrow * Hsz + mych] = h;

        asm volatile("s_waitcnt vmcnt(0)" ::: "memory");  // h stores acked @ IC
        __syncthreads();                                   // whole wg drained
        if (tid == 0)   // RELAXED (not release): ordering via vmcnt, no wbl2
            __hip_atomic_store(&flags[myflag], t + 1, __ATOMIC_RELAXED,
                               __HIP_MEMORY_SCOPE_AGENT);
    }
}

// ---------------------------------------------------------------------------
extern "C" void kernel_launch(void* const* d_in, const int* in_sizes, int n_in,
                              void* d_out, int out_size, void* d_ws, size_t ws_size,
                              hipStream_t stream) {
    const float* emb = (const float*)d_in[0];
    const float* h0  = (const float*)d_in[1];
    const float* Wx  = (const float*)d_in[2];
    const float* bx  = (const float*)d_in[3];
    const float* Wh  = (const float*)d_in[4];
    const float* bh  = (const float*)d_in[5];
    float* out = (float*)d_out;
    int* flags = (int*)d_ws;   // 256*16 ints; 0xAA poison is negative => no init

    hipLaunchKernelGGL(xp_gemm_f32, dim3(2048), dim3(256), 0, stream,
                       emb, Wx, bx, out);
    hipLaunchKernelGGL(rnn_scan_f32, dim3(256), dim3(256), 0, stream,
                       h0, Wh, bh, out, flags);
}